// Round 8
// baseline (546.495 us; speedup 1.0000x reference)
//
#include <hip/hip_runtime.h>
#include <math.h>

#define N_NODES 256
#define T_DIM   30000
#define H_DIM   512
#define L_DIM   256

// ---------------- P = I + C ----------------
__global__ void k_init_P(float* P, float* dem) {
    int t = blockIdx.x * blockDim.x + threadIdx.x; // 65536 threads
    P[t] = ((t >> 8) == (t & 255)) ? 1.0f : 0.0f;
    if (t == 0) *dem = 0.0f;
}

__global__ void k_count_edges(const int* __restrict__ idx, int E, float* P) {
    int e = blockIdx.x * blockDim.x + threadIdx.x;
    if (e < E) {
        int s = idx[e];
        int d = idx[E + e];
        atomicAdd(&P[d * N_NODES + s], 1.0f);
    }
}

__global__ void k_zero(float* p, int n) {
    int t = blockIdx.x * blockDim.x + threadIdx.x;
    if (t < n) p[t] = 0.0f;
}

// ---------------- big GEMM: Y1 = x @ Ws1a ---------------- (kernel unchanged)
template<bool ATOMIC>
__global__ __launch_bounds__(256)
void k_gemm_big(const float* __restrict__ x, const float* __restrict__ W,
                float* __restrict__ outp, int kc) {
    __shared__ float xs[16 * 140];
    __shared__ float ws[16 * 132];

    const int t  = threadIdx.x;
    const int bx = blockIdx.x;
    const int by = blockIdx.y;
    const int z  = blockIdx.z;
    const int rowBase = by * 128;
    const int colBase = bx * 128;
    const int kb0  = z * kc;
    const int kend = min(kb0 + kc, T_DIM);
    const int nchunk = (kend > kb0) ? ((kend - kb0) >> 4) : 0;

    const int lr  = t >> 2;
    const int lkq = (t & 3) * 4;
    const int wkk = t >> 5;
    const int wcq = (t & 31) * 4;
    const int tx  = t & 15, ty = t >> 4;

    float acc[8][8];
    #pragma unroll
    for (int i = 0; i < 8; ++i)
        #pragma unroll
        for (int j = 0; j < 8; ++j) acc[i][j] = 0.0f;

    if (nchunk > 0) {
        float4 xa, xb, wa, wb;
        {
            const float* xp = x + (size_t)(rowBase + lr) * T_DIM + kb0 + lkq;
            xa = *(const float4*)xp;
            xb = *(const float4*)(xp + (size_t)64 * T_DIM);
            const float* wp = W + (size_t)(kb0 + wkk) * H_DIM + colBase + wcq;
            wa = *(const float4*)wp;
            wb = *(const float4*)(wp + 8 * H_DIM);
        }

        for (int c = 0; c < nchunk; ++c) {
            __syncthreads();
            xs[(lkq + 0) * 140 + lr] = xa.x;
            xs[(lkq + 1) * 140 + lr] = xa.y;
            xs[(lkq + 2) * 140 + lr] = xa.z;
            xs[(lkq + 3) * 140 + lr] = xa.w;
            xs[(lkq + 0) * 140 + lr + 64] = xb.x;
            xs[(lkq + 1) * 140 + lr + 64] = xb.y;
            xs[(lkq + 2) * 140 + lr + 64] = xb.z;
            xs[(lkq + 3) * 140 + lr + 64] = xb.w;
            *(float4*)&ws[wkk * 132 + wcq]       = wa;
            *(float4*)&ws[(wkk + 8) * 132 + wcq] = wb;
            __syncthreads();

            if (c + 1 < nchunk) {
                int kb = kb0 + (c + 1) * 16;
                const float* xp = x + (size_t)(rowBase + lr) * T_DIM + kb + lkq;
                xa = *(const float4*)xp;
                xb = *(const float4*)(xp + (size_t)64 * T_DIM);
                const float* wp = W + (size_t)(kb + wkk) * H_DIM + colBase + wcq;
                wa = *(const float4*)wp;
                wb = *(const float4*)(wp + 8 * H_DIM);
            }

            #pragma unroll
            for (int kk = 0; kk < 16; ++kk) {
                float a[8], b[8];
                *(float4*)&a[0] = *(const float4*)&xs[kk * 140 + ty * 8];
                *(float4*)&a[4] = *(const float4*)&xs[kk * 140 + ty * 8 + 4];
                *(float4*)&b[0] = *(const float4*)&ws[kk * 132 + tx * 8];
                *(float4*)&b[4] = *(const float4*)&ws[kk * 132 + tx * 8 + 4];
                #pragma unroll
                for (int i = 0; i < 8; ++i)
                    #pragma unroll
                    for (int j = 0; j < 8; ++j)
                        acc[i][j] = fmaf(a[i], b[j], acc[i][j]);
            }
        }
    }

    if (ATOMIC) {
        if (nchunk == 0) return;
        #pragma unroll
        for (int i = 0; i < 8; ++i) {
            int r = rowBase + ty * 8 + i;
            #pragma unroll
            for (int j = 0; j < 8; ++j)
                atomicAdd(&outp[r * H_DIM + colBase + tx * 8 + j], acc[i][j]);
        }
    } else {
        float* op = outp + (size_t)z * (N_NODES * H_DIM);
        #pragma unroll
        for (int i = 0; i < 8; ++i) {
            int r = rowBase + ty * 8 + i;
            *(float4*)&op[r * H_DIM + colBase + tx * 8]     = *(float4*)&acc[i][0];
            *(float4*)&op[r * H_DIM + colBase + tx * 8 + 4] = *(float4*)&acc[i][4];
        }
    }
}

// reduce split-K partials -> Y1 (32768 float4 threads)
__global__ void k_reduce(const float4* __restrict__ Y1p, float4* __restrict__ Y1,
                         int nz) {
    int i = blockIdx.x * blockDim.x + threadIdx.x;
    float4 s = Y1p[i];
    for (int z = 1; z < nz; ++z) {
        float4 v = Y1p[(size_t)z * 32768 + i];
        s.x += v.x; s.y += v.y; s.z += v.z; s.w += v.w;
    }
    Y1[i] = s;
}

// ---------------- fused chain: 1 row/block, float4 streams ----------------
__device__ __forceinline__ float4 f4add(float4 a, float4 b) {
    float4 r; r.x=a.x+b.x; r.y=a.y+b.y; r.z=a.z+b.z; r.w=a.w+b.w; return r;
}
__device__ __forceinline__ float4 f4relu(float4 a) {
    float4 r; r.x=fmaxf(a.x,0.f); r.y=fmaxf(a.y,0.f);
    r.z=fmaxf(a.z,0.f); r.w=fmaxf(a.w,0.f); return r;
}
__device__ __forceinline__ void f4fma(float4& acc, float s, float4 v) {
    acc.x = fmaf(s, v.x, acc.x); acc.y = fmaf(s, v.y, acc.y);
    acc.z = fmaf(s, v.z, acc.z); acc.w = fmaf(s, v.w, acc.w);
}
__device__ __forceinline__ float sigmoidf(float x) {
    return 1.0f / (1.0f + expf(-x));
}

// F1: h1r[r,:] = relu( relu(P[r,:]@Y1 + bs1a) @ Ws1b + bs1b )
// 256 blocks x 256 thr: cg = t&127 (float4 col group), kh = t>>7 (k-split 2)
__global__ __launch_bounds__(256)
void k_f1(const float* __restrict__ P, const float4* __restrict__ Y4,
          const float4* __restrict__ b1a4, const float4* __restrict__ W1b4,
          const float4* __restrict__ b1b4, float4* __restrict__ h14) {
    __shared__ float prow[256];
    __shared__ float t1s[512];
    __shared__ float4 part[2][128];
    const int t = threadIdx.x, r = blockIdx.x;
    const int cg = t & 127, kh = t >> 7;
    prow[t] = P[r * 256 + t];
    __syncthreads();
    float4 a = {0.f,0.f,0.f,0.f};
    #pragma unroll 16
    for (int k = kh * 128; k < kh * 128 + 128; ++k)
        f4fma(a, prow[k], Y4[k * 128 + cg]);
    part[kh][cg] = a;
    __syncthreads();
    if (kh == 0) {
        float4 v = f4relu(f4add(f4add(part[0][cg], part[1][cg]), b1a4[cg]));
        *(float4*)&t1s[cg * 4] = v;
    }
    __syncthreads();
    float4 a2 = {0.f,0.f,0.f,0.f};
    #pragma unroll 16
    for (int k = kh * 256; k < kh * 256 + 256; ++k)
        f4fma(a2, t1s[k], W1b4[k * 128 + cg]);
    part[kh][cg] = a2;
    __syncthreads();
    if (kh == 0)
        h14[r * 128 + cg] =
            f4relu(f4add(f4add(part[0][cg], part[1][cg]), b1b4[cg]));
}

// F2: A2=P[r,:]@h1r; t2=relu(A2@Ws2a+b); feat=t2@Ws2b+b; dem += feat.Wd
__global__ __launch_bounds__(256)
void k_f2(const float* __restrict__ P, const float4* __restrict__ h14,
          const float4* __restrict__ W2a4, const float4* __restrict__ b2a4,
          const float4* __restrict__ W2b4, const float4* __restrict__ b2b4,
          const float4* __restrict__ Wd4, float4* __restrict__ feat4,
          float* __restrict__ dem) {
    __shared__ float prow[256];
    __shared__ float a2s[512];
    __shared__ float t2s[256];
    __shared__ float4 part[256];     // viewed [2][128] or [4][64]
    __shared__ float red[4];
    const int t = threadIdx.x, r = blockIdx.x;
    const int cg = t & 127, kh = t >> 7;
    const int cq = t & 63,  kq = t >> 6;
    prow[t] = P[r * 256 + t];
    __syncthreads();
    // A2 = P@h1r [512], K=256, 2-way k-split
    float4 a = {0.f,0.f,0.f,0.f};
    #pragma unroll 16
    for (int k = kh * 128; k < kh * 128 + 128; ++k)
        f4fma(a, prow[k], h14[k * 128 + cg]);
    part[kh * 128 + cg] = a;
    __syncthreads();
    if (kh == 0)
        *(float4*)&a2s[cg * 4] = f4add(part[cg], part[128 + cg]);
    __syncthreads();
    // t2 = relu(A2@Ws2a + b) [256], K=512, 4-way k-split
    float4 s = {0.f,0.f,0.f,0.f};
    #pragma unroll 16
    for (int k = kq * 128; k < kq * 128 + 128; ++k)
        f4fma(s, a2s[k], W2a4[k * 64 + cq]);
    part[kq * 64 + cq] = s;
    __syncthreads();
    if (kq == 0) {
        float4 v = f4add(f4add(part[cq], part[64 + cq]),
                         f4add(part[128 + cq], part[192 + cq]));
        *(float4*)&t2s[cq * 4] = f4relu(f4add(v, b2a4[cq]));
    }
    __syncthreads();
    // feat = t2@Ws2b + b [256], K=256, 4-way k-split
    float4 s2 = {0.f,0.f,0.f,0.f};
    #pragma unroll 16
    for (int k = kq * 64; k < kq * 64 + 64; ++k)
        f4fma(s2, t2s[k], W2b4[k * 64 + cq]);
    __syncthreads();   // a2s/t2s reads done before part reuse is fine; part rewrite:
    part[kq * 64 + cq] = s2;
    __syncthreads();
    float demp = 0.f;
    if (kq == 0) {
        float4 f = f4add(f4add(part[cq], part[64 + cq]),
                         f4add(part[128 + cq], part[192 + cq]));
        f = f4add(f, b2b4[cq]);
        feat4[r * 64 + cq] = f;
        float4 wd = Wd4[r * 64 + cq];
        demp = f.x*wd.x + f.y*wd.y + f.z*wd.z + f.w*wd.w;
    }
    #pragma unroll
    for (int off = 32; off; off >>= 1) demp += __shfl_down(demp, off, 64);
    if ((t & 63) == 0) red[t >> 6] = demp;
    __syncthreads();
    if (t == 0) atomicAdd(dem, red[0] + red[1] + red[2] + red[3]);
}

// F3: A3=P[r,:]@feat; t3=relu(A3@Wc1a+b); s1=relu(t3@Wc1b+b); u[r]=s1.Wc2a
__global__ __launch_bounds__(256)
void k_f3(const float* __restrict__ P, const float4* __restrict__ feat4,
          const float4* __restrict__ Wc1a4, const float4* __restrict__ bc1a4,
          const float4* __restrict__ Wc1b4, const float4* __restrict__ bc1b4,
          const float4* __restrict__ Wc2a4, float* __restrict__ u) {
    __shared__ float prow[256];
    __shared__ float a3s[256];
    __shared__ float t3s[512];
    __shared__ float4 part[256];
    __shared__ float red[4];
    const int t = threadIdx.x, r = blockIdx.x;
    const int cg = t & 127, kh = t >> 7;
    const int cq = t & 63,  kq = t >> 6;
    prow[t] = P[r * 256 + t];
    __syncthreads();
    // A3 = P@feat [256], K=256, 4-way k-split (no bias/relu)
    float4 s = {0.f,0.f,0.f,0.f};
    #pragma unroll 16
    for (int k = kq * 64; k < kq * 64 + 64; ++k)
        f4fma(s, prow[k], feat4[k * 64 + cq]);
    part[kq * 64 + cq] = s;
    __syncthreads();
    if (kq == 0) {
        float4 v = f4add(f4add(part[cq], part[64 + cq]),
                         f4add(part[128 + cq], part[192 + cq]));
        *(float4*)&a3s[cq * 4] = v;
    }
    __syncthreads();
    // t3 = relu(A3@Wc1a + b) [512], K=256, 2-way
    float4 a = {0.f,0.f,0.f,0.f};
    #pragma unroll 16
    for (int k = kh * 128; k < kh * 128 + 128; ++k)
        f4fma(a, a3s[k], Wc1a4[k * 128 + cg]);
    part[kh * 128 + cg] = a;
    __syncthreads();
    if (kh == 0)
        *(float4*)&t3s[cg * 4] =
            f4relu(f4add(f4add(part[cg], part[128 + cg]), bc1a4[cg]));
    __syncthreads();
    // s1 = relu(t3@Wc1b + b) [512], K=512, 2-way; u = s1 . Wc2a
    float4 a2 = {0.f,0.f,0.f,0.f};
    #pragma unroll 16
    for (int k = kh * 256; k < kh * 256 + 256; ++k)
        f4fma(a2, t3s[k], Wc1b4[k * 128 + cg]);
    part[kh * 128 + cg] = a2;
    __syncthreads();
    float up = 0.f;
    if (kh == 0) {
        float4 s1 = f4relu(f4add(f4add(part[cg], part[128 + cg]), bc1b4[cg]));
        float4 wc = Wc2a4[cg];
        up = s1.x*wc.x + s1.y*wc.y + s1.z*wc.z + s1.w*wc.w;
    }
    #pragma unroll
    for (int off = 32; off; off >>= 1) up += __shfl_down(up, off, 64);
    if ((t & 63) == 0) red[t >> 6] = up;
    __syncthreads();
    if (t == 0) u[r] = red[0] + red[1] + red[2] + red[3];
}

// F4: v = P@u per row -> region scores; block 0 emits dementia pred
__global__ __launch_bounds__(256)
void k_final(const float* __restrict__ P, const float* __restrict__ u,
             const float* __restrict__ dem,
             const float* __restrict__ bc2a, const float* __restrict__ Wc2b,
             const float* __restrict__ bc2b, const float* __restrict__ bd,
             float* __restrict__ out) {
    __shared__ float red[4];
    const int b = blockIdx.x, t = threadIdx.x;
    float pv = P[b * 256 + t] * u[t];
    #pragma unroll
    for (int off = 32; off; off >>= 1) pv += __shfl_down(pv, off, 64);
    if ((t & 63) == 0) red[t >> 6] = pv;
    __syncthreads();
    if (t == 0) {
        float v = red[0] + red[1] + red[2] + red[3];
        float h2 = fmaxf(v + bc2a[0], 0.f);
        out[1 + b] = sigmoidf(h2 * Wc2b[0] + bc2b[0]);
        if (b == 0) out[0] = sigmoidf(*dem + bd[0]);
    }
}

extern "C" void kernel_launch(void* const* d_in, const int* in_sizes, int n_in,
                              void* d_out, int out_size, void* d_ws, size_t ws_size,
                              hipStream_t stream) {
    const float* x    = (const float*)d_in[0];
    const int*   idx  = (const int*)d_in[1];
    const float* Ws1a = (const float*)d_in[3];
    const float* bs1a = (const float*)d_in[4];
    const float* Ws1b = (const float*)d_in[5];
    const float* bs1b = (const float*)d_in[6];
    const float* Ws2a = (const float*)d_in[7];
    const float* bs2a = (const float*)d_in[8];
    const float* Ws2b = (const float*)d_in[9];
    const float* bs2b = (const float*)d_in[10];
    const float* Wc1a = (const float*)d_in[11];
    const float* bc1a = (const float*)d_in[12];
    const float* Wc1b = (const float*)d_in[13];
    const float* bc1b = (const float*)d_in[14];
    const float* Wc2a = (const float*)d_in[15];
    const float* bc2a = (const float*)d_in[16];
    const float* Wc2b = (const float*)d_in[17];
    const float* bc2b = (const float*)d_in[18];
    const float* Wd   = (const float*)d_in[19];
    const float* bd   = (const float*)d_in[20];
    float* out = (float*)d_out;
    const int E = in_sizes[1] / 2;

    float* w    = (float*)d_ws;
    float* P    = w;                  // 65536
    float* Y1   = P + 65536;          // 131072
    float* h1r  = Y1 + 131072;        // 131072
    float* feat = h1r + 131072;       // 65536
    float* u    = feat + 65536;       // 256
    float* dem  = u + 256;            // 64 (dem + pad)
    float* Y1p  = dem + 64;

    // split-K slices that fit in remaining workspace (target 125 -> ~4 blk/CU)
    const long long fixed = (long long)(Y1p - w);
    const long long avail = (long long)(ws_size / 4) - fixed;
    int maxsplit = (avail > 0) ? (int)(avail / 131072) : 0;
    int nz = 0, kc = 0;
    const int CH = 1875;  // 30000/16 k-chunks
    if (maxsplit >= 2) {
        int splits = maxsplit < 125 ? maxsplit : 125;
        int chunks = (CH + splits - 1) / splits;
        nz = (CH + chunks - 1) / chunks;
        kc = chunks * 16;
    }

    // P = I + C; zero dem
    k_init_P<<<256, 256, 0, stream>>>(P, dem);
    k_count_edges<<<(E + 255) / 256, 256, 0, stream>>>(idx, E, P);

    // Y1 = x @ Ws1a   (P@(x@W) == (P@x)@W)
    if (nz > 0) {
        k_gemm_big<false><<<dim3(4, 2, nz), 256, 0, stream>>>(x, Ws1a, Y1p, kc);
        k_reduce<<<128, 256, 0, stream>>>((const float4*)Y1p, (float4*)Y1, nz);
    } else {
        k_zero<<<512, 256, 0, stream>>>(Y1, N_NODES * H_DIM);
        k_gemm_big<true><<<dim3(4, 2, 63), 256, 0, stream>>>(x, Ws1a, Y1, 480);
    }

    // fused chain: float4-vectorized row kernels (stream order = barrier)
    k_f1<<<256, 256, 0, stream>>>(P, (const float4*)Y1, (const float4*)bs1a,
                                  (const float4*)Ws1b, (const float4*)bs1b,
                                  (float4*)h1r);
    k_f2<<<256, 256, 0, stream>>>(P, (const float4*)h1r, (const float4*)Ws2a,
                                  (const float4*)bs2a, (const float4*)Ws2b,
                                  (const float4*)bs2b, (const float4*)Wd,
                                  (float4*)feat, dem);
    k_f3<<<256, 256, 0, stream>>>(P, (const float4*)feat, (const float4*)Wc1a,
                                  (const float4*)bc1a, (const float4*)Wc1b,
                                  (const float4*)bc1b, (const float4*)Wc2a, u);
    k_final<<<256, 256, 0, stream>>>(P, u, dem, bc2a, Wc2b, bc2b, bd, out);
}

// Round 9
// 291.374 us; speedup vs baseline: 1.8756x; 1.8756x over previous
//
#include <hip/hip_runtime.h>
#include <math.h>

#define N_NODES 256
#define T_DIM   30000
#define T_PAD   30016   // 938 * 32
#define H_DIM   512
#define L_DIM   256

typedef __attribute__((ext_vector_type(8))) short short8;
typedef __attribute__((ext_vector_type(4))) float floatx4;

// ---------------- P = I + C ----------------
__global__ void k_init_P(float* P, float* dem, float* u) {
    int t = blockIdx.x * blockDim.x + threadIdx.x; // 65536 threads
    P[t] = ((t >> 8) == (t & 255)) ? 1.0f : 0.0f;
    if (t == 0) *dem = 0.0f;
    if (t < 256) u[t] = 0.0f;
}

__global__ void k_count_edges(const int* __restrict__ idx, int E, float* P) {
    int e = blockIdx.x * blockDim.x + threadIdx.x;
    if (e < E) {
        int s = idx[e];
        int d = idx[E + e];
        atomicAdd(&P[d * N_NODES + s], 1.0f);
    }
}

__global__ void k_zero(float* p, int n) {
    int t = blockIdx.x * blockDim.x + threadIdx.x;
    if (t < n) p[t] = 0.0f;
}

// fp32 -> bf16 (RNE)
__device__ __forceinline__ unsigned short f2b(float f) {
    unsigned u = __float_as_uint(f);
    u += 0x7fffu + ((u >> 16) & 1u);
    return (unsigned short)(u >> 16);
}

__device__ __forceinline__ float4 zero4() {
    float4 z; z.x = z.y = z.z = z.w = 0.f; return z;
}

// ---------------- MFMA big GEMM: Y1p[z] = x @ Ws1a (K-slice z) ----------------
// x [256,30000] fp32 rm, W [30000,512] fp32 rm. grid (4 colt, 2 rowt, nz).
// 128x128 tile; BK=32; in-kernel fp32->bf16; B transposed into LDS [col][k].
__global__ __launch_bounds__(256)
void k_gemm_mfma(const float* __restrict__ x, const float* __restrict__ W,
                 float* __restrict__ outp, int kc) {
    __shared__ unsigned short Al[128 * 40]; // [row][k0..31] pad40 (80B, 16B-aligned rows)
    __shared__ unsigned short Bl[128 * 40]; // [col][k0..31] pad40

    const int t = threadIdx.x;
    const int colBase = blockIdx.x << 7;
    const int rowBase = blockIdx.y << 7;
    const int z = blockIdx.z;
    const int kb0 = z * kc;
    const int kend = min(kb0 + kc, T_PAD);
    const int nchunk = (kend - kb0) >> 5;

    // A staging: 2 threads/row, 16 consecutive k each
    const int s_row  = t >> 1;
    const int s_half = (t & 1) << 4;
    // B staging: k-major (32 k rows), 16 cols per thread
    const int s_k  = t & 31;
    const int s_cq = (t >> 5) << 4;

    // wave / fragment indexing
    const int w    = t >> 6;
    const int wr   = (w >> 1) << 6;   // wave row offset 0/64
    const int wc   = (w & 1) << 6;    // wave col offset 0/64
    const int lane = t & 63;
    const int lm   = lane & 15;
    const int lq   = (lane >> 4) << 3; // k offset 0,8,16,24

    floatx4 acc[4][4];
    #pragma unroll
    for (int i = 0; i < 4; ++i)
        #pragma unroll
        for (int j = 0; j < 4; ++j)
            acc[i][j] = (floatx4){0.f, 0.f, 0.f, 0.f};

    float4 pa[4], pb[4];
    {   // prefetch chunk 0
        const int kg = kb0;
        const float* ap = x + (size_t)(rowBase + s_row) * T_DIM + kg + s_half;
        #pragma unroll
        for (int i = 0; i < 4; ++i)
            pa[i] = (kg + s_half + i * 4 + 4 <= T_DIM) ? *(const float4*)(ap + i * 4)
                                                       : zero4();
        const float* bp = W + (size_t)(kg + s_k) * H_DIM + colBase + s_cq;
        #pragma unroll
        for (int i = 0; i < 4; ++i)
            pb[i] = (kg + s_k < T_DIM) ? *(const float4*)(bp + i * 4) : zero4();
    }

    #pragma unroll 1
    for (int c = 0; c < nchunk; ++c) {
        __syncthreads();
        // A: convert 16 floats -> 4x ds_write_b64
        #pragma unroll
        for (int i = 0; i < 4; ++i) {
            ushort4 uv;
            uv.x = f2b(pa[i].x); uv.y = f2b(pa[i].y);
            uv.z = f2b(pa[i].z); uv.w = f2b(pa[i].w);
            *(ushort4*)&Al[s_row * 40 + s_half + i * 4] = uv;
        }
        // B: transpose-convert, 16 scalar u16 writes (<=4-way conflicts)
        #pragma unroll
        for (int i = 0; i < 4; ++i) {
            const int cb = s_cq + i * 4;
            Bl[(cb + 0) * 40 + s_k] = f2b(pb[i].x);
            Bl[(cb + 1) * 40 + s_k] = f2b(pb[i].y);
            Bl[(cb + 2) * 40 + s_k] = f2b(pb[i].z);
            Bl[(cb + 3) * 40 + s_k] = f2b(pb[i].w);
        }
        __syncthreads();

        if (c + 1 < nchunk) { // register prefetch next chunk
            const int kg = kb0 + (c + 1) * 32;
            const float* ap = x + (size_t)(rowBase + s_row) * T_DIM + kg + s_half;
            #pragma unroll
            for (int i = 0; i < 4; ++i)
                pa[i] = (kg + s_half + i * 4 + 4 <= T_DIM)
                            ? *(const float4*)(ap + i * 4) : zero4();
            const float* bp = W + (size_t)(kg + s_k) * H_DIM + colBase + s_cq;
            #pragma unroll
            for (int i = 0; i < 4; ++i)
                pb[i] = (kg + s_k < T_DIM) ? *(const float4*)(bp + i * 4) : zero4();
        }

        short8 af[4], bf[4];
        #pragma unroll
        for (int i = 0; i < 4; ++i)
            af[i] = *(const short8*)&Al[(wr + i * 16 + lm) * 40 + lq];
        #pragma unroll
        for (int j = 0; j < 4; ++j)
            bf[j] = *(const short8*)&Bl[(wc + j * 16 + lm) * 40 + lq];
        #pragma unroll
        for (int i = 0; i < 4; ++i)
            #pragma unroll
            for (int j = 0; j < 4; ++j)
                acc[i][j] = __builtin_amdgcn_mfma_f32_16x16x32_bf16(
                    af[i], bf[j], acc[i][j], 0, 0, 0);
    }

    // epilogue: D rows = quad*4+reg, col = lane&15 (m89-verified layout)
    float* op = outp + (size_t)z * (N_NODES * H_DIM);
    const int rq = (lane >> 4) << 2;
    #pragma unroll
    for (int i = 0; i < 4; ++i) {
        #pragma unroll
        for (int j = 0; j < 4; ++j) {
            const int r  = rowBase + wr + i * 16 + rq;
            const int cc = colBase + wc + j * 16 + lm;
            op[(size_t)(r + 0) * H_DIM + cc] = acc[i][j][0];
            op[(size_t)(r + 1) * H_DIM + cc] = acc[i][j][1];
            op[(size_t)(r + 2) * H_DIM + cc] = acc[i][j][2];
            op[(size_t)(r + 3) * H_DIM + cc] = acc[i][j][3];
        }
    }
}

// fallback fp32 GEMM (atomic) if workspace too small for partials
__global__ __launch_bounds__(256)
void k_gemm_big_atomic(const float* __restrict__ x, const float* __restrict__ W,
                       float* __restrict__ outp, int kc) {
    __shared__ float xs[16 * 140];
    __shared__ float ws[16 * 132];
    const int t  = threadIdx.x;
    const int colBase = blockIdx.x * 128;
    const int rowBase = blockIdx.y * 128;
    const int kb0  = blockIdx.z * kc;
    const int kend = min(kb0 + kc, T_DIM);
    const int nchunk = (kend > kb0) ? ((kend - kb0) >> 4) : 0;
    const int lr  = t >> 2, lkq = (t & 3) * 4;
    const int wkk = t >> 5, wcq = (t & 31) * 4;
    const int tx  = t & 15, ty = t >> 4;
    float acc[8][8];
    #pragma unroll
    for (int i = 0; i < 8; ++i)
        #pragma unroll
        for (int j = 0; j < 8; ++j) acc[i][j] = 0.0f;
    #pragma unroll 1
    for (int c = 0; c < nchunk; ++c) {
        int kb = kb0 + c * 16;
        __syncthreads();
        const float* xp = x + (size_t)(rowBase + lr) * T_DIM + kb + lkq;
        float4 xa = *(const float4*)xp;
        float4 xb = *(const float4*)(xp + (size_t)64 * T_DIM);
        const float* wp = W + (size_t)(kb + wkk) * H_DIM + colBase + wcq;
        float4 wa = *(const float4*)wp;
        float4 wb = *(const float4*)(wp + 8 * H_DIM);
        xs[(lkq + 0) * 140 + lr] = xa.x; xs[(lkq + 1) * 140 + lr] = xa.y;
        xs[(lkq + 2) * 140 + lr] = xa.z; xs[(lkq + 3) * 140 + lr] = xa.w;
        xs[(lkq + 0) * 140 + lr + 64] = xb.x; xs[(lkq + 1) * 140 + lr + 64] = xb.y;
        xs[(lkq + 2) * 140 + lr + 64] = xb.z; xs[(lkq + 3) * 140 + lr + 64] = xb.w;
        *(float4*)&ws[wkk * 132 + wcq]       = wa;
        *(float4*)&ws[(wkk + 8) * 132 + wcq] = wb;
        __syncthreads();
        #pragma unroll
        for (int kk = 0; kk < 16; ++kk) {
            float a[8], b[8];
            *(float4*)&a[0] = *(const float4*)&xs[kk * 140 + ty * 8];
            *(float4*)&a[4] = *(const float4*)&xs[kk * 140 + ty * 8 + 4];
            *(float4*)&b[0] = *(const float4*)&ws[kk * 132 + tx * 8];
            *(float4*)&b[4] = *(const float4*)&ws[kk * 132 + tx * 8 + 4];
            #pragma unroll
            for (int i = 0; i < 8; ++i)
                #pragma unroll
                for (int j = 0; j < 8; ++j)
                    acc[i][j] = fmaf(a[i], b[j], acc[i][j]);
        }
    }
    if (nchunk == 0) return;
    #pragma unroll
    for (int i = 0; i < 8; ++i) {
        int r = rowBase + ty * 8 + i;
        #pragma unroll
        for (int j = 0; j < 8; ++j)
            atomicAdd(&outp[r * H_DIM + colBase + tx * 8 + j], acc[i][j]);
    }
}

// reduce split-K partials -> Y1 (32768 float4 threads)
__global__ void k_reduce(const float4* __restrict__ Y1p, float4* __restrict__ Y1,
                         int nz) {
    int i = blockIdx.x * blockDim.x + threadIdx.x;
    float4 s = Y1p[i];
    for (int z = 1; z < nz; ++z) {
        float4 v = Y1p[(size_t)z * 32768 + i];
        s.x += v.x; s.y += v.y; s.z += v.z; s.w += v.w;
    }
    Y1[i] = s;
}

// ---------------- stage GEMM: 8x32 tiles, 1 output/thread ----------------
// out[256 x N] = act(A[256 x K] @ B[K x N] + bias)
// grid = 32 row-tiles x (N/32) col-tiles; N=512 -> 512 blocks (2/CU).
// MODE 0: store; MODE 1: + dementia dot; MODE 2: u-fuse, no store.
template<int K, int N, int MODE>
__global__ __launch_bounds__(256)
void k_stage(const float* __restrict__ A, const float* __restrict__ B,
             const float* __restrict__ bias, float* __restrict__ out, int act,
             const float* __restrict__ Wd, float* __restrict__ dem,
             const float* __restrict__ uW, float* __restrict__ u) {
    __shared__ float As[64 * 9];    // [k][row] pad9
    __shared__ float Bs[64 * 36];   // [k][col] pad36
    __shared__ float red[4];
    const int nct = N >> 5;
    const int b = blockIdx.x;
    const int r0 = (b / nct) << 3;
    const int c0 = (b % nct) << 5;
    const int t  = threadIdx.x;
    const int row = t >> 5, col = t & 31;
    const int ar = t >> 5, ak = (t & 31) * 2;     // A: float2/thread
    const int bkr = t >> 2, bc8 = (t & 3) * 8;    // B: 8 floats/thread

    float acc = 0.f;
    // unroll 1 is load-bearing (R5: full unroll -> VGPR256 + 4KB/thr spill)
    #pragma unroll 1
    for (int kb = 0; kb < K; kb += 64) {
        __syncthreads();
        float2 av = *(const float2*)&A[(size_t)(r0 + ar) * K + kb + ak];
        As[(ak + 0) * 9 + ar] = av.x;
        As[(ak + 1) * 9 + ar] = av.y;
        const float* bp = &B[(size_t)(kb + bkr) * N + c0 + bc8];
        *(float4*)&Bs[bkr * 36 + bc8]     = *(const float4*)bp;
        *(float4*)&Bs[bkr * 36 + bc8 + 4] = *(const float4*)(bp + 4);
        __syncthreads();
        #pragma unroll
        for (int kk = 0; kk < 64; ++kk)
            acc = fmaf(As[kk * 9 + row], Bs[kk * 36 + col], acc);
    }
    const int rr = r0 + row, cc = c0 + col;
    float v = acc + (bias ? bias[cc] : 0.f);
    if (act) v = fmaxf(v, 0.f);

    if (MODE == 2) {
        float s = v * uW[cc];
        #pragma unroll
        for (int off = 16; off; off >>= 1) s += __shfl_down(s, off, 32);
        if ((t & 31) == 0) atomicAdd(&u[rr], s);
        return;
    }
    out[(size_t)rr * N + cc] = v;
    if (MODE == 1) {
        float p = v * Wd[rr * 256 + cc];
        #pragma unroll
        for (int off = 32; off; off >>= 1) p += __shfl_down(p, off, 64);
        __syncthreads();
        if ((t & 63) == 0) red[t >> 6] = p;
        __syncthreads();
        if (t == 0) atomicAdd(dem, red[0] + red[1] + red[2] + red[3]);
    }
}

__device__ __forceinline__ float sigmoidf(float x) {
    return 1.0f / (1.0f + expf(-x));
}

// final: v = P@u per row -> region scores; block 0 emits dementia pred
__global__ __launch_bounds__(256)
void k_final(const float* __restrict__ P, const float* __restrict__ u,
             const float* __restrict__ dem,
             const float* __restrict__ bc2a, const float* __restrict__ Wc2b,
             const float* __restrict__ bc2b, const float* __restrict__ bd,
             float* __restrict__ out) {
    __shared__ float red[4];
    const int b = blockIdx.x, t = threadIdx.x;
    float pv = P[b * 256 + t] * u[t];
    #pragma unroll
    for (int off = 32; off; off >>= 1) pv += __shfl_down(pv, off, 64);
    if ((t & 63) == 0) red[t >> 6] = pv;
    __syncthreads();
    if (t == 0) {
        float v = red[0] + red[1] + red[2] + red[3];
        float h2 = fmaxf(v + bc2a[0], 0.f);
        out[1 + b] = sigmoidf(h2 * Wc2b[0] + bc2b[0]);
        if (b == 0) out[0] = sigmoidf(*dem + bd[0]);
    }
}

extern "C" void kernel_launch(void* const* d_in, const int* in_sizes, int n_in,
                              void* d_out, int out_size, void* d_ws, size_t ws_size,
                              hipStream_t stream) {
    const float* x    = (const float*)d_in[0];
    const int*   idx  = (const int*)d_in[1];
    const float* Ws1a = (const float*)d_in[3];
    const float* bs1a = (const float*)d_in[4];
    const float* Ws1b = (const float*)d_in[5];
    const float* bs1b = (const float*)d_in[6];
    const float* Ws2a = (const float*)d_in[7];
    const float* bs2a = (const float*)d_in[8];
    const float* Ws2b = (const float*)d_in[9];
    const float* bs2b = (const float*)d_in[10];
    const float* Wc1a = (const float*)d_in[11];
    const float* bc1a = (const float*)d_in[12];
    const float* Wc1b = (const float*)d_in[13];
    const float* bc1b = (const float*)d_in[14];
    const float* Wc2a = (const float*)d_in[15];
    const float* bc2a = (const float*)d_in[16];
    const float* Wc2b = (const float*)d_in[17];
    const float* bc2b = (const float*)d_in[18];
    const float* Wd   = (const float*)d_in[19];
    const float* bd   = (const float*)d_in[20];
    float* out = (float*)d_out;
    const int E = in_sizes[1] / 2;

    float* w    = (float*)d_ws;
    float* P    = w;                  // 65536
    float* Y1   = P + 65536;          // 131072
    float* bufA = Y1 + 131072;        // 131072
    float* bufB = bufA + 131072;      // 131072
    float* feat = bufB + 131072;      // 65536
    float* u    = feat + 65536;       // 256
    float* dem  = u + 256;            // 64 (dem + pad)
    float* Y1p  = dem + 64;

    // split-K slicing for the MFMA GEMM: 938 chunks of BK=32 (T_PAD=30016)
    const long long fixed = (long long)(Y1p - w);
    const long long avail = (long long)(ws_size / 4) - fixed;
    int maxsplit = (avail > 0) ? (int)(avail / 131072) : 0;
    int nz = 0, kc = 0;
    const int CH32 = 938;
    if (maxsplit >= 2) {
        int splits = maxsplit < 56 ? maxsplit : 56;
        int cps = (CH32 + splits - 1) / splits;
        nz = (CH32 + cps - 1) / cps;
        kc = cps * 32;
    }

    // P = I + C; zero dem, u
    k_init_P<<<256, 256, 0, stream>>>(P, dem, u);
    k_count_edges<<<(E + 255) / 256, 256, 0, stream>>>(idx, E, P);

    // Y1 = x @ Ws1a   (P@(x@W) == (P@x)@W)   — bf16 MFMA, split-K
    if (nz > 0) {
        k_gemm_mfma<<<dim3(4, 2, nz), 256, 0, stream>>>(x, Ws1a, Y1p, kc);
        k_reduce<<<128, 256, 0, stream>>>((const float4*)Y1p, (float4*)Y1, nz);
    } else {
        k_zero<<<512, 256, 0, stream>>>(Y1, N_NODES * H_DIM);
        k_gemm_big_atomic<<<dim3(4, 2, 63), 256, 0, stream>>>(x, Ws1a, Y1, 480);
    }

    // stage chain (stream order is the barrier); 8x32 tiles, 2 blocks/CU
    k_stage<256, 512, 0><<<512, 256, 0, stream>>>(P,    Y1,   bs1a, bufA, 1, 0, 0, 0, 0);
    k_stage<512, 512, 0><<<512, 256, 0, stream>>>(bufA, Ws1b, bs1b, bufB, 1, 0, 0, 0, 0);
    k_stage<256, 512, 0><<<512, 256, 0, stream>>>(P,    bufB, 0,    bufA, 0, 0, 0, 0, 0);
    k_stage<512, 256, 0><<<256, 256, 0, stream>>>(bufA, Ws2a, bs2a, bufB, 1, 0, 0, 0, 0);
    k_stage<256, 256, 1><<<256, 256, 0, stream>>>(bufB, Ws2b, bs2b, feat, 0, Wd, dem, 0, 0);
    k_stage<256, 256, 0><<<256, 256, 0, stream>>>(P,    feat, 0,    bufA, 0, 0, 0, 0, 0);
    k_stage<256, 512, 0><<<512, 256, 0, stream>>>(bufA, Wc1a, bc1a, bufB, 1, 0, 0, 0, 0);
    k_stage<512, 512, 2><<<512, 256, 0, stream>>>(bufB, Wc1b, bc1b, 0,    1, 0, 0, Wc2a, u);
    k_final<<<256, 256, 0, stream>>>(P, u, dem, bc2a, Wc2b, bc2b, bd, out);
}